// Round 6
// baseline (265.382 us; speedup 1.0000x reference)
//
#include <hip/hip_runtime.h>

#define NPTS 65536
#define MM_BLOCKS 64

// packed fp32 pair: maps to VGPR-pair, ops select v_pk_fma_f32 (2 FMA/instr).
typedef float v2f __attribute__((ext_vector_type(2)));

// ---------------------------------------------------------------------------
// fast tanh: tanh(x) = 1 - 2/(e^{2x}+1). Saturates correctly at +-inf, no NaN.
// ---------------------------------------------------------------------------
__device__ __forceinline__ float fast_tanh(float x) {
  float e = __expf(2.0f * x);
  float r = __builtin_amdgcn_rcpf(e + 1.0f);
  return fmaf(-2.0f, r, 1.0f);
}

// ---------------------------------------------------------------------------
// Univariate order-3 jet, PACKED: {v,c1} and {c2,c3} as float2 pairs.
// macc = 2x v_pk_fma_f32 instead of 4x v_fmac_f32 -- the kernel is ~85% macc,
// and scalar f32 FMA runs at HALF the gfx950 fp32 issue ceiling (157 TF is
// pk-only).  Same fmaf semantics/order as the scalar form -> bit-identical.
// 4 float components max (6-comp jets spill, round 2: 1.5 GB scratch).
// ---------------------------------------------------------------------------
struct J3 {
  v2f vc;  // {v, c1}
  v2f cc;  // {c2, c3}
  __device__ __forceinline__ static J3 seed(float bias) {
    J3 z; z.vc = (v2f){bias, 0.f}; z.cc = (v2f){0.f, 0.f}; return z;
  }
  __device__ __forceinline__ void macc(float w, const J3& o) {
    v2f w2 = {w, w};
    vc = __builtin_elementwise_fma(w2, o.vc, vc);
    cc = __builtin_elementwise_fma(w2, o.cc, cc);
  }
  __device__ __forceinline__ J3 chain() const {
    float c1 = vc.y, c2 = cc.x, c3 = cc.y;
    float s    = fast_tanh(vc.x);
    float fp   = fmaf(-s, s, 1.0f);             // 1 - s^2
    float fpp  = -2.0f * s * fp;                // -2 s (1-s^2)
    float fppp = fmaf(6.0f * s, s, -2.0f) * fp; // (6 s^2 - 2)(1 - s^2)
    J3 r;
    r.vc = (v2f){s, fp * c1};
    r.cc = (v2f){fmaf(fpp, c1 * c1, fp * c2),
                 fmaf(fppp * c1, c1 * c1, fmaf(3.0f * fpp, c1 * c2, fp * c3))};
    return r;
  }
};

// ---------------------------------------------------------------------------
// Mixed second-order jet, PACKED: {v,a} and {b,m}.
// ---------------------------------------------------------------------------
struct JM {
  v2f va;  // {v, a}
  v2f bm;  // {b, m}
  __device__ __forceinline__ static JM seed(float bias) {
    JM z; z.va = (v2f){bias, 0.f}; z.bm = (v2f){0.f, 0.f}; return z;
  }
  __device__ __forceinline__ void macc(float w, const JM& o) {
    v2f w2 = {w, w};
    va = __builtin_elementwise_fma(w2, o.va, va);
    bm = __builtin_elementwise_fma(w2, o.bm, bm);
  }
  __device__ __forceinline__ JM chain() const {
    float a = va.y, b = bm.x, m = bm.y;
    float s   = fast_tanh(va.x);
    float fp  = fmaf(-s, s, 1.0f);
    float fpp = -2.0f * s * fp;
    JM r;
    r.va = (v2f){s, fp * a};
    r.bm = (v2f){fp * b, fmaf(fpp, a * b, fp * m)};
    return r;
  }
};

// ---------------------------------------------------------------------------
// One dense layer + tanh over a jet type.  WT TRANSPOSED in LDS so the
// unrolled i-loop reads consecutive floats (ds_read_b128, wave-uniform
// address = broadcast).
// ---------------------------------------------------------------------------
template <class J, int DIN, int DOUT>
__device__ __forceinline__ void layerT(const float* __restrict__ WT,
                                       const float* __restrict__ bias,
                                       const J* in, J* out) {
#pragma unroll
  for (int j = 0; j < DOUT; ++j) {
    J z = J::seed(bias[j]);
#pragma unroll
    for (int i = 0; i < DIN; ++i) z.macc(WT[j * DIN + i], in[i]);
    out[j] = z.chain();
  }
}

// LDS layout (floats): L0 W@0(9) b@9(3) | L1 W@12(60) b@72(20)
// | L2..L6 stride 420: W@92+420l(400) b@+400(20) | L7 W@2192(40) b@2232(2)
#define LDS_W_FLOATS 2234

// ROUND-0 COPY-BACK FORM -- DO NOT "optimize" into explicit ping-pong.
// Empirical A/B across rounds 0/3/4: with ONE layerT<20,20> instance in a
// rolled loop + B->A copy, the allocator keeps both jet arrays in registers
// (round 5: FETCH 725 KB, WRITE 1280 KB = zero spill).  With THREE unrolled
// layerT<20,20> instances (ping-pong), it spills the jet buffers: 440 MB-1 GB
// of scratch traffic and occupancy collapse.  The copy v_movs are noise.
template <class J>
__device__ __forceinline__ void run_net(const float* __restrict__ w, J* A, J* O) {
  J B[20];
  layerT<J, 3, 3>(w + 0, w + 9, A, B);
  layerT<J, 3, 20>(w + 12, w + 72, B, A);
#pragma unroll 1
  for (int l = 0; l < 5; ++l) {   // keep rolled: hot body stays in I-cache
    const float* Wl = w + 92 + l * 420;
    layerT<J, 20, 20>(Wl, Wl + 400, A, B);
#pragma unroll
    for (int jj = 0; jj < 20; ++jj) A[jj] = B[jj];
  }
  layerT<J, 20, 2>(w + 2192, w + 2232, A, O);
}

// ---------------------------------------------------------------------------
// min/max of X[:,0] via monotone-uint keys; one partial pair per block,
// butterfly-reduced per wave inside pinn_main.
// ---------------------------------------------------------------------------
__device__ __forceinline__ unsigned flipk(float f) {
  unsigned u = __float_as_uint(f);
  return (u & 0x80000000u) ? ~u : (u | 0x80000000u);
}
__device__ __forceinline__ float unflip(unsigned k) {
  unsigned u = (k & 0x80000000u) ? (k ^ 0x80000000u) : ~k;
  return __uint_as_float(u);
}

__global__ void __launch_bounds__(256) mm_reduce(const float* __restrict__ X,
                                                 unsigned* __restrict__ mm) {
  __shared__ unsigned smin[4], smax[4];
  unsigned kmin = 0xFFFFFFFFu, kmax = 0u;
  for (int i = blockIdx.x * 256 + threadIdx.x; i < NPTS; i += gridDim.x * 256) {
    unsigned key = flipk(X[3 * i]);
    kmin = min(kmin, key);
    kmax = max(kmax, key);
  }
#pragma unroll
  for (int o = 32; o > 0; o >>= 1) {
    kmin = min(kmin, (unsigned)__shfl_down((int)kmin, o, 64));
    kmax = max(kmax, (unsigned)__shfl_down((int)kmax, o, 64));
  }
  int wv = threadIdx.x >> 6;
  if ((threadIdx.x & 63) == 0) { smin[wv] = kmin; smax[wv] = kmax; }
  __syncthreads();
  if (threadIdx.x == 0) {
    kmin = min(min(smin[0], smin[1]), min(smin[2], smin[3]));
    kmax = max(max(smax[0], smax[1]), max(smax[2], smax[3]));
    mm[2 * blockIdx.x + 0] = kmin;
    mm[2 * blockIdx.x + 1] = kmax;
  }
}

// ---------------------------------------------------------------------------
// Main kernel: TWO THREADS PER POINT, identical code path for every thread
// (pass seeds are DATA selected by lane parity q -- no divergence).  Each
// thread runs 3 sequential packed 4-comp passes.
// Residency ladder (measured r0/r3/r5): 128 VGPR + 256-thr -> 2 blocks/CU;
// >=252 VGPR -> 1 block/CU (the m69 "~256" halving boundary is BELOW 252).
// The jet buffers need ~190 live floats, so <=128 VGPR is unreachable without
// GB-scale spills (r3) -- occupancy is pinned at 1 wave/SIMD; the only lever
// left is fewer VALU issue cycles, hence packed fp32.
// PLAIN __launch_bounds__(256): (256,2) caps 128 VGPR -> spills (r3);
// (256,1) lets 6-comp jets blow past 256 -> spills (r2).
// run_net MUST stay copy-back (see comment there).
//   q=0: J3 d=(k,0,0) -> psi_x,psi_xx,psi_xxx,p,p_x; J3 d=(k,k,0) -> S2p,S3p;
//        JM a=x,b=t -> psi_xt
//   q=1: J3 d=(0,k,0) -> psi_y,psi_yy,psi_yyy,p_y;   J3 d=(k,-k,0) -> S2m,S3m;
//        JM a=y,b=t -> psi_yt
// Pair combine: 7 shfl_xor(...,1), even lane assembles + stores.
// ---------------------------------------------------------------------------
__global__ void __launch_bounds__(256) pinn_main(
    const float* __restrict__ X,
    const float* W1, const float* b1, const float* W2, const float* b2,
    const float* W3, const float* b3, const float* W4, const float* b4,
    const float* W5, const float* b5, const float* W6, const float* b6,
    const float* W7, const float* b7, const float* W8, const float* b8,
    const float* lam1p, const float* lam2p, const unsigned* __restrict__ mm,
    float* __restrict__ out) {
  __shared__ float w[LDS_W_FLOATS];
  {
    const float* Wsrc[8] = {W1, W2, W3, W4, W5, W6, W7, W8};
    const float* bsrc[8] = {b1, b2, b3, b4, b5, b6, b7, b8};
    const int dinA[8]  = {3, 3, 20, 20, 20, 20, 20, 20};
    const int doutA[8] = {3, 20, 20, 20, 20, 20, 20, 2};
    const int offW[8]  = {0, 12, 92, 512, 932, 1352, 1772, 2192};
    const int offB[8]  = {9, 72, 492, 912, 1332, 1752, 2172, 2232};
#pragma unroll
    for (int a = 0; a < 8; ++a) {
      const int din = dinA[a], dout = doutA[a], nw = din * dout;
      for (int s = threadIdx.x; s < nw; s += 256) {
        int row = s / dout, col = s % dout;  // compile-time dout -> magic mul
        w[offW[a] + col * din + row] = Wsrc[a][s];  // transposed store
      }
      for (int s = threadIdx.x; s < dout; s += 256) w[offB[a] + s] = bsrc[a][s];
    }
  }

  const int lane = threadIdx.x & 63;
  const int gid  = blockIdx.x * 256 + threadIdx.x;
  const int pt   = gid >> 1;          // point index (two lanes per point)
  const int q    = gid & 1;           // 0: x-family, 1: y-family

  // global min/max: lane l holds block-partial l, butterfly across the wave
  unsigned pmin = mm[2 * lane + 0];
  unsigned pmax = mm[2 * lane + 1];
#pragma unroll
  for (int o = 1; o < 64; o <<= 1) {
    pmin = min(pmin, (unsigned)__shfl_xor((int)pmin, o, 64));
    pmax = max(pmax, (unsigned)__shfl_xor((int)pmax, o, 64));
  }
  float lb = unflip(pmin);
  float ub = unflip(pmax);
  float kk = 2.0f / (ub - lb);

  float x = X[3 * pt], y = X[3 * pt + 1], tt = X[3 * pt + 2];
  float h0 = fmaf(kk, x - lb, -1.0f);
  float h1 = fmaf(kk, y - lb, -1.0f);
  float h2 = fmaf(kk, tt - lb, -1.0f);

  __syncthreads();  // weights staged

  // pass-A / pass-B first-deriv seeds, parity-selected (cndmask, no branch)
  float a0 = q ? 0.0f : kk, a1 = q ? kk : 0.0f;   // pass A: x-dir / y-dir
  float b1s = q ? -kk : kk;                        // pass B: (k,+-k,0)

  float rc1 = 0, rc2 = 0, rc3 = 0, rpv = 0, rpc = 0;  // pass A results
  float s2 = 0, s3 = 0;                                // pass B results

#pragma unroll 1
  for (int ph = 0; ph < 2; ++ph) {
    J3 A[20], O[2];
    float d0 = ph ? kk  : a0;
    float d1 = ph ? b1s : a1;
    A[0].vc = (v2f){h0, d0};  A[0].cc = (v2f){0.f, 0.f};
    A[1].vc = (v2f){h1, d1};  A[1].cc = (v2f){0.f, 0.f};
    A[2].vc = (v2f){h2, 0.f}; A[2].cc = (v2f){0.f, 0.f};
    run_net<J3>(w, A, O);
    if (ph == 0) {
      rc1 = O[0].vc.y; rc2 = O[0].cc.x; rc3 = O[0].cc.y;
      rpv = O[1].vc.x; rpc = O[1].vc.y;
    } else {
      s2 = O[0].cc.x; s3 = O[0].cc.y;
    }
  }

  float rm;
  {
    JM A[20], O[2];
    A[0].va = (v2f){h0, a0};  A[0].bm = (v2f){0.f, 0.f};
    A[1].va = (v2f){h1, a1};  A[1].bm = (v2f){0.f, 0.f};
    A[2].va = (v2f){h2, 0.f}; A[2].bm = (v2f){kk, 0.f};
    run_net<JM>(w, A, O);
    rm = O[0].bm.y;   // psi_xt (q=0) / psi_yt (q=1)
  }

  // pair exchange: even lane receives the y-family values
  float psi_y   = __shfl_xor(rc1, 1, 64);
  float psi_yy  = __shfl_xor(rc2, 1, 64);
  float psi_yyy = __shfl_xor(rc3, 1, 64);
  float p_y     = __shfl_xor(rpc, 1, 64);
  float S2m     = __shfl_xor(s2, 1, 64);
  float S3m     = __shfl_xor(s3, 1, 64);
  float psi_yt  = __shfl_xor(rm, 1, 64);

  if (q == 0) {
    float psi_x = rc1, psi_xx = rc2, psi_xxx = rc3;
    float p_val = rpv, p_x = rpc;
    float S2p = s2, S3p = s3;
    float psi_xt = rm;

    // polarization identities
    float psi_xy  = 0.25f * (S2p - S2m);
    float psi_xxy = (S3p - S3m - 2.0f * psi_yyy) * (1.0f / 6.0f);
    float psi_xyy = (S3p + S3m - 2.0f * psi_xxx) * (1.0f / 6.0f);

    float u = psi_y, vv = -psi_x;
    float u_x = psi_xy,  u_y = psi_yy,  u_t = psi_yt;
    float v_x = -psi_xx, v_y = -psi_xy, v_t = -psi_xt;
    float u_xx = psi_xxy,  u_yy = psi_yyy;
    float v_xx = -psi_xxx, v_yy = -psi_xyy;

    float lam1 = lam1p[0], lam2 = lam2p[0];
    float f_u = u_t + lam1 * (u * u_x + vv * u_y) + p_x - lam2 * (u_xx + u_yy);
    float f_v = v_t + lam1 * (u * v_x + vv * v_y) + p_y - lam2 * (v_xx + v_yy);

    out[pt] = u;
    out[NPTS + pt] = vv;
    out[2 * NPTS + pt] = p_val;
    out[3 * NPTS + pt] = f_u;
    out[4 * NPTS + pt] = f_v;
  }
}

extern "C" void kernel_launch(void* const* d_in, const int* in_sizes, int n_in,
                              void* d_out, int out_size, void* d_ws, size_t ws_size,
                              hipStream_t stream) {
  (void)in_sizes; (void)n_in; (void)out_size; (void)ws_size;
  const float* X = (const float*)d_in[0];
  const float* W[8]; const float* B[8];
  for (int i = 0; i < 8; ++i) {
    W[i] = (const float*)d_in[1 + 2 * i];
    B[i] = (const float*)d_in[2 + 2 * i];
  }
  const float* lam1 = (const float*)d_in[17];
  const float* lam2 = (const float*)d_in[18];
  unsigned* mm = (unsigned*)d_ws;
  float* out = (float*)d_out;

  hipLaunchKernelGGL(mm_reduce, dim3(MM_BLOCKS), dim3(256), 0, stream, X, mm);
  hipLaunchKernelGGL(pinn_main, dim3(2 * NPTS / 256), dim3(256), 0, stream,
                     X, W[0], B[0], W[1], B[1], W[2], B[2], W[3], B[3],
                     W[4], B[4], W[5], B[5], W[6], B[6], W[7], B[7],
                     lam1, lam2, mm, out);
}